// Round 9
// baseline (888.416 us; speedup 1.0000x reference)
//
#include <hip/hip_runtime.h>

// Batched Jacobi diffusion, B=8, 128x128, iters=1000.
// Round 22 (= r21 resubmitted; bench infra failed with the same signature as
// r4, which passed on identical resubmit). MULTI-LAUNCH ghost zones.
// In-kernel cross-block sync is dead (r16 ~2000cy/step scoped-atomic; r19
// ~800cy/step threadfence L2-writeback storm; r20 sc0sc1-IC protocol hang:
// the flag-zeroing kernel's plain stores sat dirty in an XCD L2 and wrote
// back DURING the main kernel, clobbering live flags). Kernel LAUNCH
// boundaries give device-wide acquire/release for free (~1-2us in a captured
// graph): 63 launches of GSTEP=16 steps; T state lives in d_ws between.
//   - 16 blocks (2/batch): upper computes rows 0..79 (owns 0..63), lower
//     computes 48..127 (owns 64..127). Ghost validity: garbage enters at the
//     cut edge and moves 1 row/step; after s<=16 steps owned rows are exact
//     (79-16=63 / 48+16=64). Exactly r19's validated arithmetic (absmax 0).
//   - RPW=5, in-place update, order {1,2,3,0,4} with 3 rolling temps:
//     live set ~52 VGPR (measured r19) -> NO AGPR churn (the single-block
//     structure's 64-coef set forced ~64 v_accvgpr_read/step, r13-r18).
//   - Per launch: recompute coefs from k (IC-resident after launch 0),
//     load T[block rows] (t0>0) or init analytically (t0==0), run 16 steps
//     in registers+LDS halos, store owned rows. Final launch computes flux.
// No flags, no atomics, no fences: stream order is the only sync.

#define GH 128
#define GW 128
#define NW 16      // waves per block
#define RPW 5      // rows per wave (80 local rows / 16 waves)
#define NT 1024
#define GSTEP 16   // steps per launch = ghost depth
#define ITERS_HOST 1000   // matches reference ITERS; kernel re-checks *iters_p

typedef float v2f __attribute__((ext_vector_type(2)));

__device__ __forceinline__ float dpp_shr1(float old_v, float src) {
    // lane l gets lane l-1's src; lane 0 (invalid) keeps old_v (= left clamp)
    return __int_as_float(__builtin_amdgcn_update_dpp(
        __float_as_int(old_v), __float_as_int(src), 0x138, 0xf, 0xf, false));
}
__device__ __forceinline__ float dpp_shl1(float old_v, float src) {
    // lane l gets lane l+1's src; lane 63 (invalid) keeps old_v (= right clamp)
    return __int_as_float(__builtin_amdgcn_update_dpp(
        __float_as_int(old_v), __float_as_int(src), 0x130, 0xf, 0xf, false));
}
// d = a * b.yx   (packed f32 mul; half-swap on src1 via op_sel)
__device__ __forceinline__ v2f pk_mul_yx(v2f a, v2f b) {
    v2f d;
    asm("v_pk_mul_f32 %0, %1, %2 op_sel:[0,1] op_sel_hi:[1,0]"
        : "=v"(d) : "v"(a), "v"(b));
    return d;
}
// d = a * b + c  (packed f32 fma)
__device__ __forceinline__ v2f pk_fma(v2f a, v2f b, v2f c) {
    v2f d;
    asm("v_pk_fma_f32 %0, %1, %2, %3 op_sel:[0,0,0] op_sel_hi:[1,1,1]"
        : "=v"(d) : "v"(a), "v"(b), "v"(c));
    return d;
}

__global__ void __launch_bounds__(NT)
jacobi_chunk_kernel(const float* __restrict__ k_all,
                    const int* __restrict__ iters_p,
                    float* __restrict__ out,
                    float* __restrict__ Tws,
                    int t0)
{
    __shared__ __align__(16) v2f sTop[2][NW][64];
    __shared__ __align__(16) v2f sBot[2][NW][64];

    const int iters = *iters_p;
    if (t0 >= iters) return;                       // uniform guard
    const int nsteps = (iters - t0 < GSTEP) ? (iters - t0) : GSTEP;

    const int blk  = blockIdx.x;
    const int half = blk >> 3;          // 0 = rows 0..79, 1 = rows 48..127
    const int b    = blk & 7;
    const int tid  = threadIdx.x;
    const int l    = tid & 63;
    const int w    = tid >> 6;
    const int base = half * 48;
    const int R0   = base + w * RPW;
    const int c0   = l * 2;
    const float* kb = k_all + b * GH * GW;
    float* Tb = Tws + b * GH * GW;

    const int wUp = (w == 0)      ? 0      : w - 1;
    const int wDn = (w == NW - 1) ? NW - 1 : w + 1;
    const bool gTop = (half == 0 && w == 0);        // Dirichlet row 0
    const bool gBot = (half == 1 && w == NW - 1);   // Dirichlet row 127

    // ---- coefs: normalized face conductivities, regrouped packing ----
    v2f rN[RPW], rS[RPW], cM[RPW], cLR[RPW];
    #pragma unroll
    for (int i = 0; i < RPW; ++i) {
        const int r  = R0 + i;
        const int ru = (r == 0)      ? 0      : r - 1;
        const int rd = (r == GH - 1) ? GH - 1 : r + 1;
        float v[2][4];
        #pragma unroll
        for (int jj = 0; jj < 2; ++jj) {
            const int c  = c0 + jj;
            const int cl = (c == 0)      ? 0      : c - 1;
            const int cr = (c == GW - 1) ? GW - 1 : c + 1;
            float kc = kb[r * GW + c];
            float kn = 0.5f * (kc + kb[ru * GW + c]);
            float ks = 0.5f * (kc + kb[rd * GW + c]);
            float kw = 0.5f * (kc + kb[r * GW + cl]);
            float ke = 0.5f * (kc + kb[r * GW + cr]);
            float inv = 1.0f / (kn + ks + kw + ke);
            v[jj][0] = kn * inv; v[jj][1] = ks * inv;
            v[jj][2] = kw * inv; v[jj][3] = ke * inv;
        }
        rN[i]  = (v2f){v[0][0], v[1][0]};
        rS[i]  = (v2f){v[0][1], v[1][1]};
        cM[i]  = (v2f){v[0][3], v[1][2]};   // (cE.x, cW.y) pairs with cc.yx
        cLR[i] = (v2f){v[0][2], v[1][3]};   // (cW.x, cE.y) pairs with (lfv,rtv)
    }

    // ---- state: analytic init (t0==0) or reload from ws ----
    v2f A[RPW];
    if (t0 == 0) {
        #pragma unroll
        for (int i = 0; i < RPW; ++i)
            A[i] = (R0 + i == 0) ? (v2f){1.0f, 1.0f} : (v2f){0.0f, 0.0f};
    } else {
        #pragma unroll
        for (int i = 0; i < RPW; ++i)
            A[i] = *(const v2f*)(Tb + (R0 + i) * GW + c0);
    }

    sTop[0][w][l] = A[0];
    sBot[0][w][l] = A[RPW - 1];
    __syncthreads();

    auto F = [&](int i, v2f up, v2f cc, v2f dn) -> v2f {
        v2f s;
        s.x = dpp_shr1(cc.x, cc.y);
        s.y = dpp_shl1(cc.y, cc.x);
        return pk_fma(rN[i], up,
               pk_fma(rS[i], dn,
               pk_fma(cLR[i], s, pk_mul_yx(cM[i], cc))));
    };

    // in-place step; order {1,2,3,0,4}: every F reads pre-step values only.
    auto stepf = [&](int rp, int wp) {
        v2f hu = sBot[rp][wUp][l];   // grid row R0-1 (old)
        v2f hd = sTop[rp][wDn][l];   // grid row R0+RPW (old)
        v2f o1 = A[1], o2 = A[2], o3 = A[3];
        A[1] = F(1, A[0], o1, o2);   // up = old A0 (updated later)
        A[2] = F(2, o1, o2, o3);
        A[3] = F(3, o2, o3, A[4]);   // dn = old A4 (updated last)
        A[0] = F(0, hu, A[0], o1);
        A[4] = F(4, o3, A[4], hd);
        if (gTop) A[0] = (v2f){1.0f, 1.0f};
        if (gBot) A[4] = (v2f){0.0f, 0.0f};
        sTop[wp][w][l] = A[0];
        sBot[wp][w][l] = A[4];
        __syncthreads();
    };

    for (int s = 0; s + 2 <= nsteps; s += 2) { stepf(0, 1); stepf(1, 0); }
    if (nsteps & 1) stepf(0, 1);

    // ---- store owned rows (upper: 0..63, lower: 64..127) ----
    #pragma unroll
    for (int i = 0; i < RPW; ++i) {
        const int r = R0 + i;
        const bool owned = (half == 0) ? (r <= 63) : (r >= 64);
        if (owned) *(v2f*)(Tb + r * GW + c0) = A[i];
    }

    // ---- flux at row 64 on the final chunk: lower blk wave 3 (rows 63..67)
    if (t0 + nsteps >= iters && half == 1 && w == 3) {
        float partial = kb[64 * GW + c0]     * (A[2].x - A[1].x)
                      + kb[64 * GW + c0 + 1] * (A[2].y - A[1].y);
        #pragma unroll
        for (int off = 32; off > 0; off >>= 1)
            partial += __shfl_down(partial, off, 64);
        if (l == 0) out[b] = -partial;
    }
}

extern "C" void kernel_launch(void* const* d_in, const int* in_sizes, int n_in,
                              void* d_out, int out_size, void* d_ws, size_t ws_size,
                              hipStream_t stream)
{
    const float* k     = (const float*)d_in[0];
    const int*   iters = (const int*)d_in[1];
    float*       out   = (float*)d_out;
    float*       Tws   = (float*)d_ws;          // 8 * 128 * 128 floats = 512 KB

    for (int t0 = 0; t0 < ITERS_HOST; t0 += GSTEP)
        jacobi_chunk_kernel<<<dim3(16), dim3(NT), 0, stream>>>(
            k, iters, out, Tws, t0);
}

// Round 11
// 585.497 us; speedup vs baseline: 1.5174x; 1.5174x over previous
//
#include <hip/hip_runtime.h>

// Batched Jacobi diffusion, B=8, 128x128, iters=1000. One 1024-thread block
// per batch. Wave-strip layout: 16 waves x 8 grid rows; lane owns a float2
// column pair. VALU-issue-bound on 8 active CUs (~83% VALU-busy there).
//
// Round 24: amdgpu_num_vgpr(128) -- the DIRECT register-budget request.
// Evidence trail: honest codegen of the step body is ~84 instr/wave/step
// (48 VOP3P + 16 DPP + 16 mandatory DPP old-movs + addressing); measured is
// ~134. The ~50 extra are pressure artifacts (v_accvgpr parking churn and/or
// loop-invariant remat) from live set ~104 > the 64-reg allocation the
// backend picks when targeting 8 waves/EU (grid is structurally 4 waves/SIMD
// -- 1 block/CU). Occupancy-shaped attributes only feed the occupancy
// CALCULATION and never moved VGPR_Count (r14/r15/r18); the AGPR clobber
// hack aborted the toolchain (r23). amdgpu_num_vgpr sets the allocator's
// budget itself. LDS-coef offload was ruled out by arithmetic: 112KB/step/CU
// of ds_read_b128 = 900-1500cy >> the churn it would remove. Multi-block /
// multi-launch alternatives all died on sync transport (r16/r19/r20/r22).
// Tell: VGPR_Count ~104-128 => dur ~360-400us. If VGPR stays 64: budget
// lever is dead; remaining headroom is only instruction shaving.

#define GH 128
#define GW 128
#define NW 16      // waves per block
#define RPW 8      // rows per wave
#define NT 1024

typedef float v2f __attribute__((ext_vector_type(2)));

// middle-first row order: halo-independent rows 2..6 first, then rows 0,1
// (consume hu), then row 7 (consumes hd).
__device__ constexpr int kOrd[RPW] = {2, 3, 4, 5, 6, 0, 1, 7};

__device__ __forceinline__ float dpp_shr1(float old_v, float src) {
    // lane l gets lane l-1's src; lane 0 (invalid) keeps old_v (= left clamp)
    return __int_as_float(__builtin_amdgcn_update_dpp(
        __float_as_int(old_v), __float_as_int(src), 0x138, 0xf, 0xf, false));
}
__device__ __forceinline__ float dpp_shl1(float old_v, float src) {
    // lane l gets lane l+1's src; lane 63 (invalid) keeps old_v (= right clamp)
    return __int_as_float(__builtin_amdgcn_update_dpp(
        __float_as_int(old_v), __float_as_int(src), 0x130, 0xf, 0xf, false));
}

// d = a * b.yx   (packed f32 mul; half-swap on src1 via op_sel, no mov needed)
__device__ __forceinline__ v2f pk_mul_yx(v2f a, v2f b) {
    v2f d;
    asm("v_pk_mul_f32 %0, %1, %2 op_sel:[0,1] op_sel_hi:[1,0]"
        : "=v"(d) : "v"(a), "v"(b));
    return d;
}
// d = a * b + c  (packed f32 fma)
__device__ __forceinline__ v2f pk_fma(v2f a, v2f b, v2f c) {
    v2f d;
    asm("v_pk_fma_f32 %0, %1, %2, %3 op_sel:[0,0,0] op_sel_hi:[1,1,1]"
        : "=v"(d) : "v"(a), "v"(b), "v"(c));
    return d;
}

__global__ void
__attribute__((amdgpu_flat_work_group_size(1024, 1024)))
__attribute__((amdgpu_waves_per_eu(4, 4)))
__attribute__((amdgpu_num_vgpr(128)))
jacobi_flux_kernel(const float* __restrict__ k_all,
                   const int* __restrict__ iters_p,
                   float* __restrict__ out)
{
    __shared__ __align__(16) v2f sTop[2][NW][64];   // 16 KB
    __shared__ __align__(16) v2f sBot[2][NW][64];   // 16 KB

    const int b   = blockIdx.x;
    const int tid = threadIdx.x;
    const int l   = tid & 63;           // lane
    const int w   = tid >> 6;           // wave 0..15
    const int R0  = w * RPW;            // first grid row of my strip
    const int c0  = l * 2;              // first grid col of my pair
    const float* kb = k_all + b * GH * GW;
    const int iters = *iters_p;

    const int wUp = (w == 0)      ? 0      : w - 1;
    const int wDn = (w == NW - 1) ? NW - 1 : w + 1;
    const bool gTop = (w == 0);
    const bool gBot = (w == NW - 1);

    // ---- one-time: normalized face conductivities, packed for the
    //      regrouped stencil: rN, rS (vertical), cM=(cE.x,cW.y), cLR=(cW.x,cE.y)
    v2f rN[RPW], rS[RPW], cM[RPW], cLR[RPW];
    #pragma unroll
    for (int i = 0; i < RPW; ++i) {
        const int r  = R0 + i;
        const int ru = (r == 0)      ? 0      : r - 1;
        const int rd = (r == GH - 1) ? GH - 1 : r + 1;
        float v[2][4];
        #pragma unroll
        for (int jj = 0; jj < 2; ++jj) {
            const int c  = c0 + jj;
            const int cl = (c == 0)      ? 0      : c - 1;
            const int cr = (c == GW - 1) ? GW - 1 : c + 1;
            float kc = kb[r * GW + c];
            float kn = 0.5f * (kc + kb[ru * GW + c]);
            float ks = 0.5f * (kc + kb[rd * GW + c]);
            float kw = 0.5f * (kc + kb[r * GW + cl]);
            float ke = 0.5f * (kc + kb[r * GW + cr]);
            float inv = 1.0f / (kn + ks + kw + ke);
            v[jj][0] = kn * inv; v[jj][1] = ks * inv;
            v[jj][2] = kw * inv; v[jj][3] = ke * inv;
        }
        rN[i]  = (v2f){v[0][0], v[1][0]};
        rS[i]  = (v2f){v[0][1], v[1][1]};
        cM[i]  = (v2f){v[0][3], v[1][2]};   // (cE.x, cW.y) pairs with cc.yx
        cLR[i] = (v2f){v[0][2], v[1][3]};   // (cW.x, cE.y) pairs with (lfv,rtv)
    }

    // ---- state ----
    v2f A[RPW], B[RPW];
    #pragma unroll
    for (int i = 0; i < RPW; ++i)
        A[i] = (R0 + i == 0) ? (v2f){1.0f, 1.0f} : (v2f){0.0f, 0.0f};

    sTop[0][w][l] = A[0];
    sBot[0][w][l] = A[RPW - 1];
    __syncthreads();

    auto step = [&](const v2f (&src)[RPW], v2f (&dst)[RPW], int rp, int wp) {
        // halo loads issued first; consumed only by rows 0,1,7 which run
        // LAST (middle-first order) so the ~120cy LDS latency is hidden.
        v2f hu = sBot[rp][wUp][l];   // grid row R0-1
        v2f hd = sTop[rp][wDn][l];   // grid row R0+RPW

        #pragma unroll
        for (int j = 0; j < RPW; ++j) {
            const int i = kOrd[j];
            v2f cc = src[i];
            // (lfv, rtv): two DPP results, used only as a packed pair
            v2f s;
            s.x = dpp_shr1(cc.x, cc.y);   // left  neighbor (clamped at col 0)
            s.y = dpp_shl1(cc.y, cc.x);   // right neighbor (clamped at col 127)
            v2f up = (i == 0)       ? hu : src[i - 1];
            v2f dn = (i == RPW - 1) ? hd : src[i + 1];
            // dst = rN*up + rS*dn + cLR*(lfv,rtv) + cM*cc.yx  (all VOP3P)
            dst[i] = pk_fma(rN[i], up,
                     pk_fma(rS[i], dn,
                     pk_fma(cLR[i], s, pk_mul_yx(cM[i], cc))));
        }
        if (gTop) dst[0]       = (v2f){1.0f, 1.0f};   // Dirichlet row 0
        if (gBot) dst[RPW - 1] = (v2f){0.0f, 0.0f};   // Dirichlet row 127

        sTop[wp][w][l] = dst[0];
        sBot[wp][w][l] = dst[RPW - 1];
        __syncthreads();
    };

    const int nPairs = iters >> 1;
    for (int it = 0; it < nPairs; ++it) {
        step(A, B, 0, 1);
        step(B, A, 1, 0);
    }
    if (iters & 1) {
        step(A, B, 0, 1);
        #pragma unroll
        for (int i = 0; i < RPW; ++i) A[i] = B[i];
    }

    // ---- flux at row 64: wave 8 holds rows 64..71 (A[0]=r64, A[1]=r65) ----
    if (w == 8) {
        float partial = kb[64 * GW + c0]     * (A[1].x - A[0].x)
                      + kb[64 * GW + c0 + 1] * (A[1].y - A[0].y);
        #pragma unroll
        for (int off = 32; off > 0; off >>= 1)
            partial += __shfl_down(partial, off, 64);
        if (l == 0) out[b] = -partial;
    }
}

extern "C" void kernel_launch(void* const* d_in, const int* in_sizes, int n_in,
                              void* d_out, int out_size, void* d_ws, size_t ws_size,
                              hipStream_t stream)
{
    const float* k     = (const float*)d_in[0];
    const int*   iters = (const int*)d_in[1];
    float*       out   = (float*)d_out;
    jacobi_flux_kernel<<<dim3(8), dim3(NT), 0, stream>>>(k, iters, out);
}

// Round 12
// 578.472 us; speedup vs baseline: 1.5358x; 1.0121x over previous
//
#include <hip/hip_runtime.h>

// Batched Jacobi diffusion, B=8, 128x128, iters=1000. One 1024-thread block
// per batch. Wave-strip layout: 16 waves x 8 grid rows; lane owns a float2
// column pair. VALU-issue-bound on 8 active CUs (~83% VALU-busy there).
//
// Round 25: force the coefficient arrays into ARCH VGPRs with empty
// inline-asm "+v" operand constraints at the top of each loop iteration.
// Why: VOP3P sources must be VGPRs (AGPR srcs are only legal on MFMA /
// v_accvgpr_*), so each coef use already materializes a v-reg -- but only
// TRANSIENTLY (accvgpr_read -> temp -> die), which is the measured ~64
// v_accvgpr_read per wave-step (134 instr vs ~78 honest). Attributes can't
// say "all 64 coef regs arch-resident SIMULTANEOUSLY"; tied "+v" asm
// operands can, and cost zero instructions. Occupancy is unchanged by
// raising arch VGPRs to ~100: waves/CU steps at vgpr=64/128/256 (m69), so
// 65..128 arch regs gives 4 waves/SIMD = exactly our 16-wave block -- the
// allocator's 64-arch + 64-AGPR split was heuristic, not resource-driven.
// History: launch_bounds(NT,4) r14, waves_per_eu(4,4) r15, +flat_wgs r18,
// amdgpu_num_vgpr(128) r24 -- all reached codegen, none moved VGPR_Count.
// Named-AGPR clobber (r23) aborted the toolchain. Multi-block/multi-launch
// died on sync transport (r16/r19/r20/r22: 2000cy/step, 800cy/step, hang,
// 9us/gap). LDS coef offload ruled out by bandwidth arithmetic (>=1024
// cy/step vs 437cy churn).
// Tell: VGPR_Count ~90-128 => dur ~360-430us. If VGPR stays 64 and dur
// flat: register war over; final move is ds_bpermute shift shave.

#define GH 128
#define GW 128
#define NW 16      // waves per block
#define RPW 8      // rows per wave
#define NT 1024

typedef float v2f __attribute__((ext_vector_type(2)));

// Force 8 v2f values to be simultaneously resident in arch VGPRs here.
// Emits no instructions; only constrains the register allocator.
#define FORCE_V8(a) asm volatile("" \
    : "+v"(a[0]), "+v"(a[1]), "+v"(a[2]), "+v"(a[3]), \
      "+v"(a[4]), "+v"(a[5]), "+v"(a[6]), "+v"(a[7]))

// middle-first row order: halo-independent rows 2..6 first, then rows 0,1
// (consume hu), then row 7 (consumes hd).
__device__ constexpr int kOrd[RPW] = {2, 3, 4, 5, 6, 0, 1, 7};

__device__ __forceinline__ float dpp_shr1(float old_v, float src) {
    // lane l gets lane l-1's src; lane 0 (invalid) keeps old_v (= left clamp)
    return __int_as_float(__builtin_amdgcn_update_dpp(
        __float_as_int(old_v), __float_as_int(src), 0x138, 0xf, 0xf, false));
}
__device__ __forceinline__ float dpp_shl1(float old_v, float src) {
    // lane l gets lane l+1's src; lane 63 (invalid) keeps old_v (= right clamp)
    return __int_as_float(__builtin_amdgcn_update_dpp(
        __float_as_int(old_v), __float_as_int(src), 0x130, 0xf, 0xf, false));
}

// d = a * b.yx   (packed f32 mul; half-swap on src1 via op_sel, no mov needed)
__device__ __forceinline__ v2f pk_mul_yx(v2f a, v2f b) {
    v2f d;
    asm("v_pk_mul_f32 %0, %1, %2 op_sel:[0,1] op_sel_hi:[1,0]"
        : "=v"(d) : "v"(a), "v"(b));
    return d;
}
// d = a * b + c  (packed f32 fma)
__device__ __forceinline__ v2f pk_fma(v2f a, v2f b, v2f c) {
    v2f d;
    asm("v_pk_fma_f32 %0, %1, %2, %3 op_sel:[0,0,0] op_sel_hi:[1,1,1]"
        : "=v"(d) : "v"(a), "v"(b), "v"(c));
    return d;
}

__global__ void
__attribute__((amdgpu_flat_work_group_size(1024, 1024)))
__attribute__((amdgpu_waves_per_eu(4, 4)))
jacobi_flux_kernel(const float* __restrict__ k_all,
                   const int* __restrict__ iters_p,
                   float* __restrict__ out)
{
    __shared__ __align__(16) v2f sTop[2][NW][64];   // 16 KB
    __shared__ __align__(16) v2f sBot[2][NW][64];   // 16 KB

    const int b   = blockIdx.x;
    const int tid = threadIdx.x;
    const int l   = tid & 63;           // lane
    const int w   = tid >> 6;           // wave 0..15
    const int R0  = w * RPW;            // first grid row of my strip
    const int c0  = l * 2;              // first grid col of my pair
    const float* kb = k_all + b * GH * GW;
    const int iters = *iters_p;

    const int wUp = (w == 0)      ? 0      : w - 1;
    const int wDn = (w == NW - 1) ? NW - 1 : w + 1;
    const bool gTop = (w == 0);
    const bool gBot = (w == NW - 1);

    // ---- one-time: normalized face conductivities, packed for the
    //      regrouped stencil: rN, rS (vertical), cM=(cE.x,cW.y), cLR=(cW.x,cE.y)
    v2f rN[RPW], rS[RPW], cM[RPW], cLR[RPW];
    #pragma unroll
    for (int i = 0; i < RPW; ++i) {
        const int r  = R0 + i;
        const int ru = (r == 0)      ? 0      : r - 1;
        const int rd = (r == GH - 1) ? GH - 1 : r + 1;
        float v[2][4];
        #pragma unroll
        for (int jj = 0; jj < 2; ++jj) {
            const int c  = c0 + jj;
            const int cl = (c == 0)      ? 0      : c - 1;
            const int cr = (c == GW - 1) ? GW - 1 : c + 1;
            float kc = kb[r * GW + c];
            float kn = 0.5f * (kc + kb[ru * GW + c]);
            float ks = 0.5f * (kc + kb[rd * GW + c]);
            float kw = 0.5f * (kc + kb[r * GW + cl]);
            float ke = 0.5f * (kc + kb[r * GW + cr]);
            float inv = 1.0f / (kn + ks + kw + ke);
            v[jj][0] = kn * inv; v[jj][1] = ks * inv;
            v[jj][2] = kw * inv; v[jj][3] = ke * inv;
        }
        rN[i]  = (v2f){v[0][0], v[1][0]};
        rS[i]  = (v2f){v[0][1], v[1][1]};
        cM[i]  = (v2f){v[0][3], v[1][2]};   // (cE.x, cW.y) pairs with cc.yx
        cLR[i] = (v2f){v[0][2], v[1][3]};   // (cW.x, cE.y) pairs with (lfv,rtv)
    }

    // ---- state ----
    v2f A[RPW], B[RPW];
    #pragma unroll
    for (int i = 0; i < RPW; ++i)
        A[i] = (R0 + i == 0) ? (v2f){1.0f, 1.0f} : (v2f){0.0f, 0.0f};

    sTop[0][w][l] = A[0];
    sBot[0][w][l] = A[RPW - 1];
    __syncthreads();

    auto step = [&](const v2f (&src)[RPW], v2f (&dst)[RPW], int rp, int wp) {
        // halo loads issued first; consumed only by rows 0,1,7 which run
        // LAST (middle-first order) so the ~120cy LDS latency is hidden.
        v2f hu = sBot[rp][wUp][l];   // grid row R0-1
        v2f hd = sTop[rp][wDn][l];   // grid row R0+RPW

        #pragma unroll
        for (int j = 0; j < RPW; ++j) {
            const int i = kOrd[j];
            v2f cc = src[i];
            // (lfv, rtv): two DPP results, used only as a packed pair
            v2f s;
            s.x = dpp_shr1(cc.x, cc.y);   // left  neighbor (clamped at col 0)
            s.y = dpp_shl1(cc.y, cc.x);   // right neighbor (clamped at col 127)
            v2f up = (i == 0)       ? hu : src[i - 1];
            v2f dn = (i == RPW - 1) ? hd : src[i + 1];
            // dst = rN*up + rS*dn + cLR*(lfv,rtv) + cM*cc.yx  (all VOP3P)
            dst[i] = pk_fma(rN[i], up,
                     pk_fma(rS[i], dn,
                     pk_fma(cLR[i], s, pk_mul_yx(cM[i], cc))));
        }
        if (gTop) dst[0]       = (v2f){1.0f, 1.0f};   // Dirichlet row 0
        if (gBot) dst[RPW - 1] = (v2f){0.0f, 0.0f};   // Dirichlet row 127

        sTop[wp][w][l] = dst[0];
        sBot[wp][w][l] = dst[RPW - 1];
        __syncthreads();
    };

    const int nPairs = iters >> 1;
    for (int it = 0; it < nPairs; ++it) {
        // Pin all 32 coef v2fs in arch VGPRs simultaneously (0 instructions).
        FORCE_V8(rN); FORCE_V8(rS); FORCE_V8(cM); FORCE_V8(cLR);
        step(A, B, 0, 1);
        step(B, A, 1, 0);
    }
    if (iters & 1) {
        step(A, B, 0, 1);
        #pragma unroll
        for (int i = 0; i < RPW; ++i) A[i] = B[i];
    }

    // ---- flux at row 64: wave 8 holds rows 64..71 (A[0]=r64, A[1]=r65) ----
    if (w == 8) {
        float partial = kb[64 * GW + c0]     * (A[1].x - A[0].x)
                      + kb[64 * GW + c0 + 1] * (A[1].y - A[0].y);
        #pragma unroll
        for (int off = 32; off > 0; off >>= 1)
            partial += __shfl_down(partial, off, 64);
        if (l == 0) out[b] = -partial;
    }
}

extern "C" void kernel_launch(void* const* d_in, const int* in_sizes, int n_in,
                              void* d_out, int out_size, void* d_ws, size_t ws_size,
                              hipStream_t stream)
{
    const float* k     = (const float*)d_in[0];
    const int*   iters = (const int*)d_in[1];
    float*       out   = (float*)d_out;
    jacobi_flux_kernel<<<dim3(8), dim3(NT), 0, stream>>>(k, iters, out);
}